// Round 1
// baseline (1961.392 us; speedup 1.0000x reference)
//
#include <hip/hip_runtime.h>
#include <hip/hip_bf16.h>
#include <math.h>

#define N_NODES 50000
#define N_EDGES 800000
#define IN_DIM 32
#define HIDDEN 64
#define Z_DIM 32

// ---------------------------------------------------------------------------
// Index dtype detection: edge_index may be int32 (JAX default) or int64
// (reference says jnp.int64). For int64 little-endian values < 2^31, every
// odd int32 word is 0. Probability of that for real int32 node ids over 512
// samples is ~0.
__global__ void detect_idx_kernel(const int* __restrict__ raw, int* __restrict__ flag) {
    if (blockIdx.x == 0 && threadIdx.x == 0) {
        int is64 = 1;
        for (int i = 1; i < 1024; i += 2) {
            if (raw[i] != 0) { is64 = 0; break; }
        }
        *flag = is64;
    }
}

__global__ void convert_idx_kernel(const void* __restrict__ raw, const int* __restrict__ flag,
                                   int* __restrict__ out, int n) {
    int i = blockIdx.x * blockDim.x + threadIdx.x;
    if (i >= n) return;
    if (*flag) {
        out[i] = (int)((const long long*)raw)[i];
    } else {
        out[i] = ((const int*)raw)[i];
    }
}

// ---------------------------------------------------------------------------
// Degree: deg[v] = in-degree(v) + 1 (self loop); then dinv = rsqrt(deg).
__global__ void init_deg_kernel(float* __restrict__ deg, int n) {
    int i = blockIdx.x * blockDim.x + threadIdx.x;
    if (i < n) deg[i] = 1.0f;
}

__global__ void count_deg_kernel(const int* __restrict__ dst, float* __restrict__ deg) {
    int e = blockIdx.x * blockDim.x + threadIdx.x;
    if (e < N_EDGES) atomicAdd(&deg[dst[e]], 1.0f);
}

__global__ void dinv_kernel(float* __restrict__ deg, int n) {
    int i = blockIdx.x * blockDim.x + threadIdx.x;
    if (i < n) deg[i] = rsqrtf(deg[i]);   // deg >= 1 always (self-loop)
}

// ---------------------------------------------------------------------------
// Aggregation out = A h  (A = normalized adjacency incl. self loop)
// Step 1: out[v] = dinv[v]^2 * h[v]   (self-loop term, also inits the buffer)
template<int D>
__global__ void agg_init_kernel(const float* __restrict__ h, const float* __restrict__ dinv,
                                float* __restrict__ out) {
    int t = blockIdx.x * blockDim.x + threadIdx.x;
    const int VPN = D / 4;            // float4 per node
    int v  = t / VPN;
    int f4 = t % VPN;
    if (v >= N_NODES) return;
    float dv = dinv[v];
    float s  = dv * dv;
    float4 hv = ((const float4*)(h + (size_t)v * D))[f4];
    float4 o;
    o.x = s * hv.x; o.y = s * hv.y; o.z = s * hv.z; o.w = s * hv.w;
    ((float4*)(out + (size_t)v * D))[f4] = o;
}

// Step 2: out[dst] += dinv[src]*dinv[dst] * h[src]  (scatter-add, f32 atomics)
template<int D>
__global__ void agg_edge_kernel(const int* __restrict__ src, const int* __restrict__ dst,
                                const float* __restrict__ dinv, const float* __restrict__ h,
                                float* __restrict__ out) {
    int t = blockIdx.x * blockDim.x + threadIdx.x;
    const int VPE = D / 4;            // float4 per edge
    int e  = t / VPE;
    int f4 = t % VPE;
    if (e >= N_EDGES) return;
    int s = src[e];
    int d = dst[e];
    float nrm = dinv[s] * dinv[d];
    float4 hv = ((const float4*)(h + (size_t)s * D))[f4];
    float* o = out + (size_t)d * D + 4 * f4;
    atomicAdd(o + 0, nrm * hv.x);
    atomicAdd(o + 1, nrm * hv.y);
    atomicAdd(o + 2, nrm * hv.z);
    atomicAdd(o + 3, nrm * hv.w);
}

// ---------------------------------------------------------------------------
// out[n, DO] = relu?(in[n, DI] @ W[DI, DO] + b)   — W staged in LDS
template<int DI, int DO, bool RELU>
__global__ void gemm_bias_kernel(const float* __restrict__ in, const float* __restrict__ W,
                                 const float* __restrict__ b, float* __restrict__ out, int n) {
    __shared__ float sW[DI * DO];
    for (int i = threadIdx.x; i < DI * DO; i += 256) sW[i] = W[i];
    __syncthreads();
    const int NPB = 256 / DO;         // nodes per block-iteration
    int of = threadIdx.x % DO;
    int nl = threadIdx.x / DO;
    float bb = b[of];
    for (int node = blockIdx.x * NPB + nl; node < n; node += gridDim.x * NPB) {
        const float* row = in + (size_t)node * DI;
        float acc = bb;
#pragma unroll
        for (int k = 0; k < DI; k++) acc = fmaf(row[k], sW[k * DO + of], acc);
        out[(size_t)node * DO + of] = RELU ? fmaxf(acc, 0.0f) : acc;
    }
}

// ---------------------------------------------------------------------------
// Heads: from a2 = A(h2)  [N, 64]:
//   mu = a2 @ Wmu + bmu ; lv = a2 @ Wlv + blv ; z = mu + exp(0.5 lv) * eps
// d_out layout: [z | mu | lv], each N*Z_DIM floats.
__global__ void head_kernel(const float* __restrict__ a2,
                            const float* __restrict__ Wmu, const float* __restrict__ bmu,
                            const float* __restrict__ Wlv, const float* __restrict__ blv,
                            const float* __restrict__ eps, float* __restrict__ outz, int n) {
    __shared__ float sWm[HIDDEN * Z_DIM];
    __shared__ float sWl[HIDDEN * Z_DIM];
    for (int i = threadIdx.x; i < HIDDEN * Z_DIM; i += 256) {
        sWm[i] = Wmu[i];
        sWl[i] = Wlv[i];
    }
    __syncthreads();
    const int NPB = 256 / Z_DIM;      // 8 nodes per block-iteration
    int f  = threadIdx.x % Z_DIM;
    int nl = threadIdx.x / Z_DIM;
    float bm = bmu[f], bl = blv[f];
    float* z  = outz;
    float* mu = outz + (size_t)N_NODES * Z_DIM;
    float* lv = outz + 2 * (size_t)N_NODES * Z_DIM;
    for (int node = blockIdx.x * NPB + nl; node < n; node += gridDim.x * NPB) {
        const float* row = a2 + (size_t)node * HIDDEN;
        float am = bm, al = bl;
#pragma unroll
        for (int k = 0; k < HIDDEN; k++) {
            float r = row[k];
            am = fmaf(r, sWm[k * Z_DIM + f], am);
            al = fmaf(r, sWl[k * Z_DIM + f], al);
        }
        size_t o = (size_t)node * Z_DIM + f;
        mu[o] = am;
        lv[o] = al;
        z[o]  = fmaf(expf(0.5f * al), eps[o], am);
    }
}

// ---------------------------------------------------------------------------
extern "C" void kernel_launch(void* const* d_in, const int* in_sizes, int n_in,
                              void* d_out, int out_size, void* d_ws, size_t ws_size,
                              hipStream_t stream) {
    const float* x   = (const float*)d_in[0];
    const void*  ei  = d_in[1];
    const float* W1  = (const float*)d_in[2];
    const float* b1  = (const float*)d_in[3];
    const float* W2  = (const float*)d_in[4];
    const float* b2  = (const float*)d_in[5];
    const float* Wmu = (const float*)d_in[6];
    const float* bmu = (const float*)d_in[7];
    const float* Wlv = (const float*)d_in[8];
    const float* blv = (const float*)d_in[9];
    const float* eps = (const float*)d_in[10];
    float* out = (float*)d_out;

    char* ws = (char*)d_ws;
    size_t off = 0;
    auto alloc = [&](size_t bytes) -> void* {
        void* p = ws + off;
        off += (bytes + 255) & ~(size_t)255;
        return p;
    };
    int*   idx  = (int*)alloc(sizeof(int) * 2 * N_EDGES);     // 6.4 MB
    int*   flag = (int*)alloc(sizeof(int) * 64);
    float* dinv = (float*)alloc(sizeof(float) * N_NODES);     // 0.2 MB
    float* B1   = (float*)alloc(sizeof(float) * (size_t)N_NODES * HIDDEN);  // 12.8 MB
    float* B2   = (float*)alloc(sizeof(float) * (size_t)N_NODES * HIDDEN);  // 12.8 MB
    (void)ws_size; (void)in_sizes; (void)n_in; (void)out_size;

    const int* srcI = idx;
    const int* dstI = idx + N_EDGES;

    // index normalization (handles int32 or int64 edge_index)
    detect_idx_kernel<<<1, 64, 0, stream>>>((const int*)ei, flag);
    convert_idx_kernel<<<(2 * N_EDGES + 255) / 256, 256, 0, stream>>>(ei, flag, idx, 2 * N_EDGES);

    // degrees -> dinv (in place)
    init_deg_kernel<<<(N_NODES + 255) / 256, 256, 0, stream>>>(dinv, N_NODES);
    count_deg_kernel<<<(N_EDGES + 255) / 256, 256, 0, stream>>>(dstI, dinv);
    dinv_kernel<<<(N_NODES + 255) / 256, 256, 0, stream>>>(dinv, N_NODES);

    // Layer 1: ax = A(x) [N,32] in B1; h1 = relu(ax@W1+b1) [N,64] in B2
    agg_init_kernel<IN_DIM><<<(N_NODES * (IN_DIM / 4) + 255) / 256, 256, 0, stream>>>(x, dinv, B1);
    agg_edge_kernel<IN_DIM><<<(N_EDGES * (IN_DIM / 4) + 255) / 256, 256, 0, stream>>>(srcI, dstI, dinv, x, B1);
    gemm_bias_kernel<IN_DIM, HIDDEN, true><<<(N_NODES + 3) / 4, 256, 0, stream>>>(B1, W1, b1, B2, N_NODES);

    // Layer 2: a1 = A(h1) [N,64] in B1; h2 = relu(a1@W2+b2) [N,64] in B2
    agg_init_kernel<HIDDEN><<<(N_NODES * (HIDDEN / 4) + 255) / 256, 256, 0, stream>>>(B2, dinv, B1);
    agg_edge_kernel<HIDDEN><<<(N_EDGES * (HIDDEN / 4) + 255) / 256, 256, 0, stream>>>(srcI, dstI, dinv, B2, B1);
    gemm_bias_kernel<HIDDEN, HIDDEN, true><<<(N_NODES + 3) / 4, 256, 0, stream>>>(B1, W2, b2, B2, N_NODES);

    // Heads: a2 = A(h2) [N,64] in B1; then mu/lv/z fused
    agg_init_kernel<HIDDEN><<<(N_NODES * (HIDDEN / 4) + 255) / 256, 256, 0, stream>>>(B2, dinv, B1);
    agg_edge_kernel<HIDDEN><<<(N_EDGES * (HIDDEN / 4) + 255) / 256, 256, 0, stream>>>(srcI, dstI, dinv, B2, B1);
    head_kernel<<<(N_NODES + 7) / 8, 256, 0, stream>>>(B1, Wmu, bmu, Wlv, blv, eps, out, N_NODES);
}

// Round 2
// 448.224 us; speedup vs baseline: 4.3759x; 4.3759x over previous
//
#include <hip/hip_runtime.h>
#include <hip/hip_bf16.h>
#include <math.h>

#define N_NODES 50000
#define N_EDGES 800000
#define IN_DIM 32
#define HIDDEN 64
#define Z_DIM 32
#define SCAN_B 256
#define NB_SCAN ((N_NODES + SCAN_B - 1) / SCAN_B)   // 196

// ---------------------------------------------------------------------------
// Index dtype detection: edge_index may be int32 (JAX default) or int64
// (reference declares jnp.int64). For int64 LE values < 2^31 every odd int32
// word is 0.
__global__ void detect_idx_kernel(const int* __restrict__ raw, int* __restrict__ flag) {
    if (blockIdx.x == 0 && threadIdx.x == 0) {
        int is64 = 1;
        for (int i = 1; i < 1024; i += 2) {
            if (raw[i] != 0) { is64 = 0; break; }
        }
        *flag = is64;
    }
}

__global__ void convert_idx_kernel(const void* __restrict__ raw, const int* __restrict__ flag,
                                   int* __restrict__ out, int n) {
    int i = blockIdx.x * blockDim.x + threadIdx.x;
    if (i >= n) return;
    if (*flag) {
        out[i] = (int)((const long long*)raw)[i];
    } else {
        out[i] = ((const int*)raw)[i];
    }
}

// ---------------------------------------------------------------------------
// CSR build: histogram -> scan -> scatter
__global__ void zero_cnt_kernel(int* __restrict__ cnt, int n) {
    int i = blockIdx.x * blockDim.x + threadIdx.x;
    if (i < n) cnt[i] = 0;
}

__global__ void hist_kernel(const int* __restrict__ dst, int* __restrict__ cnt) {
    int e = blockIdx.x * blockDim.x + threadIdx.x;
    if (e < N_EDGES) atomicAdd(&cnt[dst[e]], 1);
}

// block-local exclusive scan; also computes dinv = rsqrt(deg+1) on the side
__global__ void scan1_kernel(const int* __restrict__ cnt, int* __restrict__ pre,
                             int* __restrict__ bsum, float* __restrict__ dinv) {
    __shared__ int s[SCAN_B];
    int t = threadIdx.x;
    int g = blockIdx.x * SCAN_B + t;
    int v = (g < N_NODES) ? cnt[g] : 0;
    if (g < N_NODES) dinv[g] = rsqrtf((float)(v + 1));   // +1 self loop
    s[t] = v;
    __syncthreads();
    for (int o = 1; o < SCAN_B; o <<= 1) {
        int add = (t >= o) ? s[t - o] : 0;
        __syncthreads();
        s[t] += add;
        __syncthreads();
    }
    if (g < N_NODES) pre[g] = s[t] - v;                  // exclusive within block
    if (t == SCAN_B - 1) bsum[blockIdx.x] = s[t];
}

__global__ void scan2_kernel(int* __restrict__ bsum, int nb) {   // single block
    __shared__ int s[256];
    int t = threadIdx.x;
    int v = (t < nb) ? bsum[t] : 0;
    s[t] = v;
    __syncthreads();
    for (int o = 1; o < 256; o <<= 1) {
        int add = (t >= o) ? s[t - o] : 0;
        __syncthreads();
        s[t] += add;
        __syncthreads();
    }
    if (t < nb) bsum[t] = s[t] - v;                      // exclusive block offsets
}

__global__ void scan3_kernel(int* __restrict__ rowptr, const int* __restrict__ bsum,
                             int* __restrict__ cursor) {
    int g = blockIdx.x * SCAN_B + threadIdx.x;
    if (g < N_NODES) {
        int r = rowptr[g] + bsum[blockIdx.x];
        rowptr[g] = r;
        cursor[g] = r;
    }
    if (g == 0) rowptr[N_NODES] = N_EDGES;
}

__global__ void scatter_kernel(const int* __restrict__ src, const int* __restrict__ dst,
                               int* __restrict__ cursor, int* __restrict__ ssrc) {
    int e = blockIdx.x * blockDim.x + threadIdx.x;
    if (e >= N_EDGES) return;
    int d = dst[e];
    int p = atomicAdd(&cursor[d], 1);
    ssrc[p] = src[e];
}

// ---------------------------------------------------------------------------
// Gather aggregation out = A h, one wave per node, lane = feature (D=64).
// out[v,f] = dv * ( dv*h[v,f] + sum_e dinv[src_e]*h[src_e,f] )
__global__ void gather64_kernel(const int* __restrict__ rowptr, const int* __restrict__ ssrc,
                                const float* __restrict__ dinv, const float* __restrict__ h,
                                float* __restrict__ out) {
    int v = blockIdx.x * (blockDim.x >> 6) + (threadIdx.x >> 6);
    int f = threadIdx.x & 63;
    if (v >= N_NODES) return;
    float dv  = dinv[v];
    float acc = dv * h[(size_t)v * 64 + f];      // self-loop (pre-factored)
    int e  = rowptr[v];
    int e1 = rowptr[v + 1];
    for (; e + 1 < e1; e += 2) {
        int s0 = ssrc[e];
        int s1 = ssrc[e + 1];
        float d0 = dinv[s0];
        float d1 = dinv[s1];
        float h0 = h[(size_t)s0 * 64 + f];
        float h1 = h[(size_t)s1 * 64 + f];
        acc = fmaf(d0, h0, acc);
        acc = fmaf(d1, h1, acc);
    }
    if (e < e1) {
        int s = ssrc[e];
        acc = fmaf(dinv[s], h[(size_t)s * 64 + f], acc);
    }
    out[(size_t)v * 64 + f] = dv * acc;
}

// D=32 variant: wave handles 2 edges at once (lane bit 5 selects edge parity),
// __shfl_down(32) combines the halves.
__global__ void gather32_kernel(const int* __restrict__ rowptr, const int* __restrict__ ssrc,
                                const float* __restrict__ dinv, const float* __restrict__ h,
                                float* __restrict__ out) {
    int v = blockIdx.x * (blockDim.x >> 6) + (threadIdx.x >> 6);
    int lane = threadIdx.x & 63;
    int f  = lane & 31;
    int eo = lane >> 5;                           // 0 or 1
    if (v >= N_NODES) return;
    float dv  = dinv[v];
    float acc = 0.0f;
    int e1 = rowptr[v + 1];
    for (int e = rowptr[v] + eo; e < e1; e += 2) {
        int s = ssrc[e];
        acc = fmaf(dinv[s], h[(size_t)s * 32 + f], acc);
    }
    acc += __shfl_down(acc, 32);                  // combine odd-edge half
    if (eo == 0) {
        out[(size_t)v * 32 + f] = dv * fmaf(dv, h[(size_t)v * 32 + f], acc);
    }
}

// ---------------------------------------------------------------------------
// out[n, DO] = relu?(in[n, DI] @ W[DI, DO] + b) — W staged in LDS
template<int DI, int DO, bool RELU>
__global__ void gemm_bias_kernel(const float* __restrict__ in, const float* __restrict__ W,
                                 const float* __restrict__ b, float* __restrict__ out, int n) {
    __shared__ float sW[DI * DO];
    for (int i = threadIdx.x; i < DI * DO; i += 256) sW[i] = W[i];
    __syncthreads();
    const int NPB = 256 / DO;
    int of = threadIdx.x % DO;
    int nl = threadIdx.x / DO;
    float bb = b[of];
    for (int node = blockIdx.x * NPB + nl; node < n; node += gridDim.x * NPB) {
        const float* row = in + (size_t)node * DI;
        float acc = bb;
#pragma unroll
        for (int k = 0; k < DI; k++) acc = fmaf(row[k], sW[k * DO + of], acc);
        out[(size_t)node * DO + of] = RELU ? fmaxf(acc, 0.0f) : acc;
    }
}

// ---------------------------------------------------------------------------
// Heads from a2 = A(h2) [N,64]: mu, logvar, z. d_out layout: [z | mu | lv].
__global__ void head_kernel(const float* __restrict__ a2,
                            const float* __restrict__ Wmu, const float* __restrict__ bmu,
                            const float* __restrict__ Wlv, const float* __restrict__ blv,
                            const float* __restrict__ eps, float* __restrict__ outz, int n) {
    __shared__ float sWm[HIDDEN * Z_DIM];
    __shared__ float sWl[HIDDEN * Z_DIM];
    for (int i = threadIdx.x; i < HIDDEN * Z_DIM; i += 256) {
        sWm[i] = Wmu[i];
        sWl[i] = Wlv[i];
    }
    __syncthreads();
    const int NPB = 256 / Z_DIM;
    int f  = threadIdx.x % Z_DIM;
    int nl = threadIdx.x / Z_DIM;
    float bm = bmu[f], bl = blv[f];
    float* z  = outz;
    float* mu = outz + (size_t)N_NODES * Z_DIM;
    float* lv = outz + 2 * (size_t)N_NODES * Z_DIM;
    for (int node = blockIdx.x * NPB + nl; node < n; node += gridDim.x * NPB) {
        const float* row = a2 + (size_t)node * HIDDEN;
        float am = bm, al = bl;
#pragma unroll
        for (int k = 0; k < HIDDEN; k++) {
            float r = row[k];
            am = fmaf(r, sWm[k * Z_DIM + f], am);
            al = fmaf(r, sWl[k * Z_DIM + f], al);
        }
        size_t o = (size_t)node * Z_DIM + f;
        mu[o] = am;
        lv[o] = al;
        z[o]  = fmaf(expf(0.5f * al), eps[o], am);
    }
}

// ---------------------------------------------------------------------------
extern "C" void kernel_launch(void* const* d_in, const int* in_sizes, int n_in,
                              void* d_out, int out_size, void* d_ws, size_t ws_size,
                              hipStream_t stream) {
    const float* x   = (const float*)d_in[0];
    const void*  ei  = d_in[1];
    const float* W1  = (const float*)d_in[2];
    const float* b1  = (const float*)d_in[3];
    const float* W2  = (const float*)d_in[4];
    const float* b2  = (const float*)d_in[5];
    const float* Wmu = (const float*)d_in[6];
    const float* bmu = (const float*)d_in[7];
    const float* Wlv = (const float*)d_in[8];
    const float* blv = (const float*)d_in[9];
    const float* eps = (const float*)d_in[10];
    float* out = (float*)d_out;
    (void)in_sizes; (void)n_in; (void)out_size; (void)ws_size;

    char* ws = (char*)d_ws;
    size_t off = 0;
    auto alloc = [&](size_t bytes) -> void* {
        void* p = ws + off;
        off += (bytes + 255) & ~(size_t)255;
        return p;
    };
    // persistent region (alive across the whole pipeline)
    int*   ssrc   = (int*)alloc(sizeof(int) * N_EDGES);          // 3.2 MB
    int*   rowptr = (int*)alloc(sizeof(int) * (N_NODES + 1));    // 0.2 MB
    int*   cursor = (int*)alloc(sizeof(int) * N_NODES);          // 0.2 MB
    int*   cnt    = (int*)alloc(sizeof(int) * N_NODES);          // 0.2 MB
    float* dinv   = (float*)alloc(sizeof(float) * N_NODES);      // 0.2 MB
    int*   flag   = (int*)alloc(sizeof(int) * 64);
    int*   bsum   = (int*)alloc(sizeof(int) * 256);
    float* B1     = (float*)alloc(sizeof(float) * (size_t)N_NODES * HIDDEN);  // 12.8 MB
    float* B2     = (float*)alloc(sizeof(float) * (size_t)N_NODES * HIDDEN);  // 12.8 MB
    // raw converted edge list is dead after scatter_kernel; alias it over B1
    // (B1 is first written by gather32_kernel, which runs after scatter_kernel)
    int* idx = (int*)B1;                                          // 6.4 MB alias
    const int* srcI = idx;
    const int* dstI = idx + N_EDGES;

    // ---- index normalization (int32 or int64 edge_index) ----
    detect_idx_kernel<<<1, 64, 0, stream>>>((const int*)ei, flag);
    convert_idx_kernel<<<(2 * N_EDGES + 255) / 256, 256, 0, stream>>>(ei, flag, idx, 2 * N_EDGES);

    // ---- CSR build (counting sort by dst) + dinv ----
    zero_cnt_kernel<<<(N_NODES + 255) / 256, 256, 0, stream>>>(cnt, N_NODES);
    hist_kernel<<<(N_EDGES + 255) / 256, 256, 0, stream>>>(dstI, cnt);
    scan1_kernel<<<NB_SCAN, SCAN_B, 0, stream>>>(cnt, rowptr, bsum, dinv);
    scan2_kernel<<<1, 256, 0, stream>>>(bsum, NB_SCAN);
    scan3_kernel<<<NB_SCAN, SCAN_B, 0, stream>>>(rowptr, bsum, cursor);
    scatter_kernel<<<(N_EDGES + 255) / 256, 256, 0, stream>>>(srcI, dstI, cursor, ssrc);

    // ---- Layer 1: ax = A(x) [N,32] -> B2's low half? use B2 as temp;
    //      then h1 = relu(ax@W1+b1) [N,64] -> B2 ... careful with aliasing:
    //      gather32 writes B2 (idx alias lives in B1, already dead), gemm B2->B1
    gather32_kernel<<<(N_NODES * 64 + 255) / 256, 256, 0, stream>>>(rowptr, ssrc, dinv, x, B2);
    gemm_bias_kernel<IN_DIM, HIDDEN, true><<<(N_NODES + 3) / 4, 256, 0, stream>>>(B2, W1, b1, B1, N_NODES);

    // ---- Layer 2: a1 = A(h1) -> B2; h2 = relu(a1@W2+b2) -> B1 ----
    gather64_kernel<<<(N_NODES * 64 + 255) / 256, 256, 0, stream>>>(rowptr, ssrc, dinv, B1, B2);
    gemm_bias_kernel<HIDDEN, HIDDEN, true><<<(N_NODES + 3) / 4, 256, 0, stream>>>(B2, W2, b2, B1, N_NODES);

    // ---- Heads: a2 = A(h2) -> B2; fused mu/lv/z ----
    gather64_kernel<<<(N_NODES * 64 + 255) / 256, 256, 0, stream>>>(rowptr, ssrc, dinv, B1, B2);
    head_kernel<<<(N_NODES + 7) / 8, 256, 0, stream>>>(B2, Wmu, bmu, Wlv, blv, eps, out, N_NODES);
}